// Round 13
// baseline (20.831 us; speedup 1.0000x reference)
//
#include <hip/hip_runtime.h>
#include <math.h>

#define DIMD 16
#define HIDN 32
#define DIAG_MIN 0.316f
#define DIAG_MAX 3.16f
#define NT 9          // ceil(136/16) N-tiles of lower triangle
#define PLSTRIDE 68   // shorts per Pl row (136B, 8B-aligned b64 writes; col reads 2-way-free)
#define HSTRIDE 36    // shorts per h-row: 72B -> b64-aligned, bank-spread
#define DXSTRIDE 20   // floats per dxs row
#define TRI(i) (((i)*((i)+1))>>1)

typedef short bf16x8 __attribute__((ext_vector_type(8)));
typedef float f32x4  __attribute__((ext_vector_type(4)));

// rc (compact lower-tri index) -> W2 row r = i*16+k
__device__ const unsigned char R_OF_RC[136] = {
    0,
    16,17,
    32,33,34,
    48,49,50,51,
    64,65,66,67,68,
    80,81,82,83,84,85,
    96,97,98,99,100,101,102,
    112,113,114,115,116,117,118,119,
    128,129,130,131,132,133,134,135,136,
    144,145,146,147,148,149,150,151,152,153,
    160,161,162,163,164,165,166,167,168,169,170,
    176,177,178,179,180,181,182,183,184,185,186,187,
    192,193,194,195,196,197,198,199,200,201,202,203,204,
    208,209,210,211,212,213,214,215,216,217,218,219,220,221,
    224,225,226,227,228,229,230,231,232,233,234,235,236,237,238,
    240,241,242,243,244,245,246,247,248,249,250,251,252,253,254,255
};

__device__ __forceinline__ short f2bf(float f) {  // RNE
    unsigned u = __float_as_uint(f);
    return (short)((u + 0x7FFFu + ((u >> 16) & 1u)) >> 16);
}
__device__ __forceinline__ float bf2f(short s) {
    return __uint_as_float(((unsigned)(unsigned short)s) << 16);
}
__device__ __forceinline__ unsigned pk(float a, float b) {
    return (unsigned)(unsigned short)f2bf(a) | ((unsigned)(unsigned short)f2bf(b) << 16);
}
__device__ __forceinline__ float silu(float x) {
    return x * __frcp_rn(1.0f + __expf(-x));
}

// Phase-B combine, fully static per wave-uniform KK.
template<int KK>
__device__ __forceinline__ float combine(const short* __restrict__ Pm,
                                         const float* __restrict__ dxr)
{
    float distp = 0.0f;
    #pragma unroll
    for (int qq = 0; qq < 4; ++qq) {
        const int k = KK + 4 * qq;
        float r = bf2f(Pm[(TRI(k) + k) * PLSTRIDE]) + 1.0f;  // +I bias
        float sp = __logf(1.0f + __expf(r));  // exact where clamp doesn't saturate
        float dg = fminf(fmaxf(sp, DIAG_MIN), DIAG_MAX);
        float y = dxr[k] * dg;
        #pragma unroll
        for (int i = k + 1; i < DIMD; ++i)
            y = fmaf(dxr[i], bf2f(Pm[(TRI(i) + k) * PLSTRIDE]), y);
        distp = fmaf(y, y, distp);
    }
    return distp;
}

// R6 structure (best measured: 18.8us) with three targeted edits:
// 1. Pl un-unioned from w2t (33.9 KB LDS, still 4 blocks/CU) -> sync2 DELETED.
// 2. b2 values gathered into 9 VGPRs pre-barrier (R7-verified) -> b2c LDS +
//    its 9 in-loop LDS reads deleted.
// 3. layer-2 MFMA / pack / Pl-write interleaved (acc liveness 1).
// Barriers 4 -> 3. Everything else identical to R6.
__global__ __launch_bounds__(256, 4) void rm_kernel(
    const float* __restrict__ x1, const float* __restrict__ x2,
    const float* __restrict__ W1, const float* __restrict__ b1,
    const float* __restrict__ W2, const float* __restrict__ b2,
    float* __restrict__ out)
{
    __shared__ __align__(16) short w2t[4608];          //  9216 B
    __shared__ __align__(16) short Pl[136 * PLSTRIDE]; // 18496 B
    __shared__ float dxs[64 * DXSTRIDE];               //  5120 B
    __shared__ float part[256];                        //  1024 B -> 33856 B

    const int tid  = threadIdx.x;
    const int lane = tid & 63;
    const int wid  = tid >> 6;
    const int blk  = blockIdx.x;
    const int mc   = blk & 3;
    const int bn   = blk >> 2;
    const int b    = bn >> 8;

    const int arow  = lane & 15;
    const int kgrp  = lane >> 4;
    const int m_loc = wid * 16 + arow;
    const int m     = mc * 64 + m_loc;

    // ---- stage W2 -> w2t (bf16, fragment-tiled, coalesced) ----
    #pragma unroll
    for (int it = 0; it < 2; ++it) {
        const int rc = it * 128 + (tid >> 1);
        if (rc < 144) {
            const int rcs = rc > 135 ? 135 : rc;       // pad rows copy rc=135
            const int r = R_OF_RC[rcs];
            const int hf = tid & 1;
            const float4* s4 = (const float4*)(W2 + r * HIDN + hf * 16);
            float4 v0 = s4[0], v1 = s4[1], v2 = s4[2], v3 = s4[3];
            uint4 wa, wb;
            wa.x = pk(v0.x, v0.y); wa.y = pk(v0.z, v0.w);
            wa.z = pk(v1.x, v1.y); wa.w = pk(v1.z, v1.w);
            wb.x = pk(v2.x, v2.y); wb.y = pk(v2.z, v2.w);
            wb.z = pk(v3.x, v3.y); wb.w = pk(v3.z, v3.w);
            const int base = (((rc >> 4) * 4 + hf * 2) * 16 + (rc & 15)) * 8;
            *(uint4*)(w2t + base)       = wa;   // kgrp = 2*hf
            *(uint4*)(w2t + base + 128) = wb;   // kgrp = 2*hf+1
        }
    }

    // ---- b2 values for this lane's 9 tiles (L1-hot gathers, 9 VGPR) ----
    float b2v[NT];
    #pragma unroll
    for (int t = 0; t < NT; ++t) {
        int rc = t * 16 + arow;
        b2v[t] = b2[R_OF_RC[rc > 135 ? 135 : rc]];
    }

    // ---- mid + dx ----
    const float4* a4 = (const float4*)(x1 + bn * DIMD);
    const float4* c4 = (const float4*)(x2 + (b * 256 + m) * DIMD);
    float mid[DIMD];
    #pragma unroll
    for (int q = 0; q < 4; ++q) {
        float4 va = a4[q], vb = c4[q];
        mid[4*q+0] = (va.x + vb.x) * 0.5f;
        mid[4*q+1] = (va.y + vb.y) * 0.5f;
        mid[4*q+2] = (va.z + vb.z) * 0.5f;
        mid[4*q+3] = (va.w + vb.w) * 0.5f;
        if (kgrp == 0) {   // 16 lanes cover this wave's 16 rows
            float4 v = {vb.x - va.x, vb.y - va.y, vb.z - va.z, vb.w - va.w};
            *(float4*)(&dxs[m_loc * DXSTRIDE + 4 * q]) = v;
        }
    }

    // ---- layer 1: H^T = W1 @ mid^T, 2 MFMAs (K padded 16->32) ----
    bf16x8 Bm;   // B[k=8kgrp+jo][m=arow] = mid[8kgrp+jo] (0 for k>=16)
    #pragma unroll
    for (int jo = 0; jo < 8; ++jo) {
        float v = kgrp == 0 ? mid[jo] : (kgrp == 1 ? mid[8 + jo] : 0.0f);
        Bm[jo] = f2bf(v);
    }
    #pragma unroll
    for (int t = 0; t < 2; ++t) {
        bf16x8 Aw = {0, 0, 0, 0, 0, 0, 0, 0};  // A[j'=arow][k] = W1[16t+arow][k]
        if (kgrp < 2) {
            const float4* wp = (const float4*)(W1 + (t * 16 + arow) * DIMD + kgrp * 8);
            float4 a = wp[0], bb = wp[1];
            Aw[0] = f2bf(a.x);  Aw[1] = f2bf(a.y);  Aw[2] = f2bf(a.z);  Aw[3] = f2bf(a.w);
            Aw[4] = f2bf(bb.x); Aw[5] = f2bf(bb.y); Aw[6] = f2bf(bb.z); Aw[7] = f2bf(bb.w);
        }
        float4 cb = *(const float4*)(b1 + t * 16 + kgrp * 4);   // C = b1[j]
        f32x4 c0 = {cb.x, cb.y, cb.z, cb.w};
        f32x4 hr = __builtin_amdgcn_mfma_f32_16x16x32_bf16(Aw, Bm, c0, 0, 0, 0);
        // lane holds h[m=arow][j = 16t + 4kgrp + q] -> 4 consecutive j: b64
        uint2 hw;
        hw.x = pk(silu(hr[0]), silu(hr[1]));
        hw.y = pk(silu(hr[2]), silu(hr[3]));
        *(uint2*)(Pl + wid * 16 * HSTRIDE + arow * HSTRIDE + t * 16 + kgrp * 4) = hw;
    }

    // ---- layer-2 A-frag: h[arow][8kgrp .. +8) (same-wave, lgkm-ordered) ----
    bf16x8 A2;
    {
        const uint2* hp = (const uint2*)(Pl + wid * 16 * HSTRIDE + arow * HSTRIDE + kgrp * 8);
        uint2 p0 = hp[0], p1 = hp[1];
        uint4 tmp = {p0.x, p0.y, p1.x, p1.y};
        A2 = *(bf16x8*)&tmp;
    }

    __syncthreads();   // sync1: w2t staged (and hls region of Pl consumed)

    // ---- layer 2: 9x {b128 B-frag, MFMA, pack, b64 Pl write} ----
    #pragma unroll
    for (int t = 0; t < NT; ++t) {
        bf16x8 B2 = *(const bf16x8*)(w2t + ((t * 4 + kgrp) * 16 + arow) * 8);
        f32x4 c0 = {b2v[t], b2v[t], b2v[t], b2v[t]};
        f32x4 acc = __builtin_amdgcn_mfma_f32_16x16x32_bf16(A2, B2, c0, 0, 0, 0);
        int rc = t * 16 + arow;
        rc = rc > 135 ? 135 : rc;   // pad lanes duplicate rc=135 (same values)
        uint2 v;
        v.x = pk(acc[0], acc[1]);
        v.y = pk(acc[2], acc[3]);
        *(uint2*)(&Pl[rc * PLSTRIDE + wid * 16 + kgrp * 4]) = v;
    }

    __syncthreads();   // sync3: Pl + dxs ready

    // ---- phase B ----
    const int cm = tid & 63;
    const int kk = __builtin_amdgcn_readfirstlane(tid >> 6);
    const short* Pm = Pl + cm;

    float dxr[DIMD];
    #pragma unroll
    for (int q = 0; q < 4; ++q) {
        float4 v = *(const float4*)(&dxs[cm * DXSTRIDE + 4 * q]);
        dxr[4*q+0] = v.x; dxr[4*q+1] = v.y; dxr[4*q+2] = v.z; dxr[4*q+3] = v.w;
    }

    float distp;
    switch (kk) {
        case 0:  distp = combine<0>(Pm, dxr); break;
        case 1:  distp = combine<1>(Pm, dxr); break;
        case 2:  distp = combine<2>(Pm, dxr); break;
        default: distp = combine<3>(Pm, dxr); break;
    }
    part[tid] = distp;

    __syncthreads();   // sync4: part ready

    if (tid < 64) {
        float d = part[tid] + part[64 + tid] + part[128 + tid] + part[192 + tid];
        out[bn * 256 + mc * 64 + tid] = __fsqrt_rn(fmaxf(d, 1e-6f));
    }
}

extern "C" void kernel_launch(void* const* d_in, const int* in_sizes, int n_in,
                              void* d_out, int out_size, void* d_ws, size_t ws_size,
                              hipStream_t stream) {
    const float* x1 = (const float*)d_in[0];
    const float* x2 = (const float*)d_in[1];
    const float* W1 = (const float*)d_in[2];
    const float* b1 = (const float*)d_in[3];
    const float* W2 = (const float*)d_in[4];
    const float* b2 = (const float*)d_in[5];
    float* out = (float*)d_out;

    rm_kernel<<<2048, 256, 0, stream>>>(x1, x2, W1, b1, W2, b2, out);
}

// Round 15
// 17.928 us; speedup vs baseline: 1.1619x; 1.1619x over previous
//
#include <hip/hip_runtime.h>
#include <hip/hip_bf16.h>
#include <math.h>

#define DIMD 16
#define HIDN 32
#define DIAG_MIN 0.316f
#define DIAG_MAX 3.16f
#define NT 9          // ceil(136/16) N-tiles of lower triangle
#define PLSTRIDE 68   // shorts per Pl row (136B, 8B-aligned b64 writes)
#define HSTRIDE 36    // shorts per h-row: 72B -> b64-aligned, bank-spread
#define DXSTRIDE 20   // floats per dxs row
#define TRI(i) (((i)*((i)+1))>>1)

typedef short bf16x8 __attribute__((ext_vector_type(8)));
typedef float f32x4  __attribute__((ext_vector_type(4)));

// rc (compact lower-tri index) -> W2 row r = i*16+k
__device__ const unsigned char R_OF_RC[136] = {
    0,
    16,17,
    32,33,34,
    48,49,50,51,
    64,65,66,67,68,
    80,81,82,83,84,85,
    96,97,98,99,100,101,102,
    112,113,114,115,116,117,118,119,
    128,129,130,131,132,133,134,135,136,
    144,145,146,147,148,149,150,151,152,153,
    160,161,162,163,164,165,166,167,168,169,170,
    176,177,178,179,180,181,182,183,184,185,186,187,
    192,193,194,195,196,197,198,199,200,201,202,203,204,
    208,209,210,211,212,213,214,215,216,217,218,219,220,221,
    224,225,226,227,228,229,230,231,232,233,234,235,236,237,238,
    240,241,242,243,244,245,246,247,248,249,250,251,252,253,254,255
};

// HW bf16 conversion via HIP intrinsic (v_cvt-class op, RNE); ROCm 7.2
// has no __floats2bfloat162_rn — build the pair from scalar casts.
__device__ __forceinline__ unsigned short f2bfu(float f) {
    __hip_bfloat16 h = __float2bfloat16(f);
    return *reinterpret_cast<unsigned short*>(&h);
}
__device__ __forceinline__ short f2bf(float f) {
    return (short)f2bfu(f);
}
__device__ __forceinline__ unsigned pk(float a, float b) {
    return (unsigned)f2bfu(a) | ((unsigned)f2bfu(b) << 16);
}
__device__ __forceinline__ float bf2f(short s) {
    return __uint_as_float(((unsigned)(unsigned short)s) << 16);
}
__device__ __forceinline__ float silu(float x) {
    return x * __frcp_rn(1.0f + __expf(-x));
}

// Phase-B combine, fully static per wave-uniform KK.
template<int KK>
__device__ __forceinline__ float combine(const short* __restrict__ Pm,
                                         const float* __restrict__ dxr)
{
    float distp = 0.0f;
    #pragma unroll
    for (int qq = 0; qq < 4; ++qq) {
        const int k = KK + 4 * qq;
        float r = bf2f(Pm[(TRI(k) + k) * PLSTRIDE]) + 1.0f;  // +I bias
        float sp = __logf(1.0f + __expf(r));  // exact where clamp doesn't saturate
        float dg = fminf(fmaxf(sp, DIAG_MIN), DIAG_MAX);
        float y = dxr[k] * dg;
        #pragma unroll
        for (int i = k + 1; i < DIMD; ++i)
            y = fmaf(dxr[i], bf2f(Pm[(TRI(i) + k) * PLSTRIDE]), y);
        distp = fmaf(y, y, distp);
    }
    return distp;
}

// EXACT R6 structure (best measured: 18.8us, replicated twice) with ONE
// change: all bf16 conversions use the HW conversion intrinsic
// (__float2bfloat16) instead of the 5-VALU manual RNE sequence.
// ~45 conversions/thread -> saves ~200+ VALU ops/thread.
// Single-variable experiment on the best kernel.
__global__ __launch_bounds__(256, 4) void rm_kernel(
    const float* __restrict__ x1, const float* __restrict__ x2,
    const float* __restrict__ W1, const float* __restrict__ b1,
    const float* __restrict__ W2, const float* __restrict__ b2,
    float* __restrict__ out)
{
    __shared__ __align__(16) char uni[136 * PLSTRIDE * 2];  // 18496 B
    __shared__ short hls[4 * 16 * HSTRIDE];                 // 4608 B
    __shared__ float dxs[64 * DXSTRIDE];                    // 5120 B
    __shared__ float part[256];                             // 1024 B
    short* w2t = (short*)uni;                 // 4608 sh = 9216 B (stage-time)
    float* b2c = (float*)(uni + 9216);        // 144 f32 = 576 B
    short* Pl  = (short*)uni;                 // overlays after sync2

    const int tid  = threadIdx.x;
    const int lane = tid & 63;
    const int wid  = tid >> 6;
    const int blk  = blockIdx.x;
    const int mc   = blk & 3;
    const int bn   = blk >> 2;
    const int b    = bn >> 8;

    const int arow  = lane & 15;
    const int kgrp  = lane >> 4;
    const int m_loc = wid * 16 + arow;
    const int m     = mc * 64 + m_loc;

    // ---- stage W2 -> w2t (bf16, fragment-tiled, coalesced) ----
    #pragma unroll
    for (int it = 0; it < 2; ++it) {
        const int rc = it * 128 + (tid >> 1);
        if (rc < 144) {
            const int rcs = rc > 135 ? 135 : rc;       // pad rows copy rc=135
            const int r = R_OF_RC[rcs];
            const int hf = tid & 1;
            const float4* s4 = (const float4*)(W2 + r * HIDN + hf * 16);
            float4 v0 = s4[0], v1 = s4[1], v2 = s4[2], v3 = s4[3];
            uint4 wa, wb;
            wa.x = pk(v0.x, v0.y); wa.y = pk(v0.z, v0.w);
            wa.z = pk(v1.x, v1.y); wa.w = pk(v1.z, v1.w);
            wb.x = pk(v2.x, v2.y); wb.y = pk(v2.z, v2.w);
            wb.z = pk(v3.x, v3.y); wb.w = pk(v3.z, v3.w);
            const int base = (((rc >> 4) * 4 + hf * 2) * 16 + (rc & 15)) * 8;
            *(uint4*)(w2t + base)       = wa;   // kgrp = 2*hf
            *(uint4*)(w2t + base + 128) = wb;   // kgrp = 2*hf+1
        }
    }
    if (tid < 144) b2c[tid] = b2[R_OF_RC[tid > 135 ? 135 : tid]];

    // ---- mid + dx ----
    const float4* a4 = (const float4*)(x1 + bn * DIMD);
    const float4* c4 = (const float4*)(x2 + (b * 256 + m) * DIMD);
    float mid[DIMD];
    #pragma unroll
    for (int q = 0; q < 4; ++q) {
        float4 va = a4[q], vb = c4[q];
        mid[4*q+0] = (va.x + vb.x) * 0.5f;
        mid[4*q+1] = (va.y + vb.y) * 0.5f;
        mid[4*q+2] = (va.z + vb.z) * 0.5f;
        mid[4*q+3] = (va.w + vb.w) * 0.5f;
        if (kgrp == 0) {   // 16 lanes cover this wave's 16 rows
            float4 v = {vb.x - va.x, vb.y - va.y, vb.z - va.z, vb.w - va.w};
            *(float4*)(&dxs[m_loc * DXSTRIDE + 4 * q]) = v;
        }
    }

    // ---- layer 1: H^T = W1 @ mid^T, 2 MFMAs (K padded 16->32) ----
    bf16x8 Bm;   // B[k=8kgrp+jo][m=arow] = mid[8kgrp+jo] (0 for k>=16)
    #pragma unroll
    for (int jo = 0; jo < 8; ++jo) {
        float v = kgrp == 0 ? mid[jo] : (kgrp == 1 ? mid[8 + jo] : 0.0f);
        Bm[jo] = f2bf(v);
    }
    #pragma unroll
    for (int t = 0; t < 2; ++t) {
        bf16x8 Aw = {0, 0, 0, 0, 0, 0, 0, 0};  // A[j'=arow][k] = W1[16t+arow][k]
        if (kgrp < 2) {
            const float4* wp = (const float4*)(W1 + (t * 16 + arow) * DIMD + kgrp * 8);
            float4 a = wp[0], bb = wp[1];
            Aw[0] = f2bf(a.x);  Aw[1] = f2bf(a.y);  Aw[2] = f2bf(a.z);  Aw[3] = f2bf(a.w);
            Aw[4] = f2bf(bb.x); Aw[5] = f2bf(bb.y); Aw[6] = f2bf(bb.z); Aw[7] = f2bf(bb.w);
        }
        float4 cb = *(const float4*)(b1 + t * 16 + kgrp * 4);   // C = b1[j]
        f32x4 c0 = {cb.x, cb.y, cb.z, cb.w};
        f32x4 hr = __builtin_amdgcn_mfma_f32_16x16x32_bf16(Aw, Bm, c0, 0, 0, 0);
        // lane holds h[m=arow][j = 16t + 4kgrp + q] -> 4 consecutive j: b64
        uint2 hw;
        hw.x = pk(silu(hr[0]), silu(hr[1]));
        hw.y = pk(silu(hr[2]), silu(hr[3]));
        *(uint2*)(hls + wid * 16 * HSTRIDE + arow * HSTRIDE + t * 16 + kgrp * 4) = hw;
    }

    // ---- layer-2 A-frag: h[arow][8kgrp .. +8) (intra-wave, no barrier) ----
    bf16x8 A2;
    {
        const uint2* hp = (const uint2*)(hls + wid * 16 * HSTRIDE + arow * HSTRIDE + kgrp * 8);
        uint2 p0 = hp[0], p1 = hp[1];
        uint4 tmp = {p0.x, p0.y, p1.x, p1.y};
        A2 = *(bf16x8*)&tmp;
    }

    __syncthreads();   // sync1: w2t/b2c staged

    // ---- layer 2: 9 MFMAs, conflict-free b128 B-frags ----
    f32x4 acc[NT];
    #pragma unroll
    for (int t = 0; t < NT; ++t) {
        bf16x8 B2 = *(const bf16x8*)(w2t + ((t * 4 + kgrp) * 16 + arow) * 8);
        const float cb = b2c[t * 16 + arow];
        f32x4 c0 = {cb, cb, cb, cb};
        acc[t] = __builtin_amdgcn_mfma_f32_16x16x32_bf16(A2, B2, c0, 0, 0, 0);
    }

    __syncthreads();   // sync2: w2t reads done; Pl may overwrite union

    // ---- Pl[rc][m] bf16: one b64 write per tile ----
    #pragma unroll
    for (int t = 0; t < NT; ++t) {
        int rc = t * 16 + arow;
        rc = rc > 135 ? 135 : rc;   // pad lanes duplicate rc=135 (same values)
        uint2 v;
        v.x = pk(acc[t][0], acc[t][1]);
        v.y = pk(acc[t][2], acc[t][3]);
        *(uint2*)(&Pl[rc * PLSTRIDE + wid * 16 + kgrp * 4]) = v;
    }

    __syncthreads();   // sync3: Pl + dxs ready

    // ---- phase B ----
    const int cm = tid & 63;
    const int kk = __builtin_amdgcn_readfirstlane(tid >> 6);
    const short* Pm = Pl + cm;

    float dxr[DIMD];
    #pragma unroll
    for (int q = 0; q < 4; ++q) {
        float4 v = *(const float4*)(&dxs[cm * DXSTRIDE + 4 * q]);
        dxr[4*q+0] = v.x; dxr[4*q+1] = v.y; dxr[4*q+2] = v.z; dxr[4*q+3] = v.w;
    }

    float distp;
    switch (kk) {
        case 0:  distp = combine<0>(Pm, dxr); break;
        case 1:  distp = combine<1>(Pm, dxr); break;
        case 2:  distp = combine<2>(Pm, dxr); break;
        default: distp = combine<3>(Pm, dxr); break;
    }
    part[tid] = distp;

    __syncthreads();   // sync4: part ready

    if (tid < 64) {
        float d = part[tid] + part[64 + tid] + part[128 + tid] + part[192 + tid];
        out[bn * 256 + mc * 64 + tid] = __fsqrt_rn(fmaxf(d, 1e-6f));
    }
}

extern "C" void kernel_launch(void* const* d_in, const int* in_sizes, int n_in,
                              void* d_out, int out_size, void* d_ws, size_t ws_size,
                              hipStream_t stream) {
    const float* x1 = (const float*)d_in[0];
    const float* x2 = (const float*)d_in[1];
    const float* W1 = (const float*)d_in[2];
    const float* b1 = (const float*)d_in[3];
    const float* W2 = (const float*)d_in[4];
    const float* b2 = (const float*)d_in[5];
    float* out = (float*)d_out;

    rm_kernel<<<2048, 256, 0, stream>>>(x1, x2, W1, b1, W2, b2, out);
}